// Round 3
// baseline (542.840 us; speedup 1.0000x reference)
//
#include <hip/hip_runtime.h>
#include <hip/hip_bf16.h>

#define H_DIM  1024
#define RANK_  4
#define BATCH_ 128
#define TSTEPS 256
#define M_DIM  (BATCH_ * TSTEPS)   // 32768

typedef __bf16 bf16x8 __attribute__((ext_vector_type(8)));
typedef float  floatx4 __attribute__((ext_vector_type(4)));
typedef unsigned short ushortx8 __attribute__((ext_vector_type(8)));

// RNE float -> bf16 (branchless; inputs are finite)
__device__ __forceinline__ unsigned short f2bf(float f) {
    unsigned u = __float_as_uint(f);
    u += 0x7FFFu + ((u >> 16) & 1u);
    return (unsigned short)(u >> 16);
}

// ---------------- conversion kernels ----------------

__global__ __launch_bounds__(256) void cvt_x_kernel(const float* __restrict__ x,
                                                    unsigned short* __restrict__ xb) {
    size_t i = ((size_t)blockIdx.x * 256 + threadIdx.x) * 8;
    float4 v0 = *(const float4*)(x + i);
    float4 v1 = *(const float4*)(x + i + 4);
    ushortx8 o;
    o[0] = f2bf(v0.x); o[1] = f2bf(v0.y); o[2] = f2bf(v0.z); o[3] = f2bf(v0.w);
    o[4] = f2bf(v1.x); o[5] = f2bf(v1.y); o[6] = f2bf(v1.z); o[7] = f2bf(v1.w);
    *(ushortx8*)(xb + i) = o;
}

// Bt[n][k] = bf16(B[k][n])
__global__ __launch_bounds__(256) void cvt_bt_kernel(const float* __restrict__ B,
                                                     unsigned short* __restrict__ Bt) {
    __shared__ float tl[32][33];
    int tx = threadIdx.x & 31, ty = threadIdx.x >> 5;   // ty in 0..7
    int k0 = blockIdx.y * 32, n0 = blockIdx.x * 32;
#pragma unroll
    for (int j = 0; j < 4; ++j)
        tl[ty + 8 * j][tx] = B[(size_t)(k0 + ty + 8 * j) * H_DIM + n0 + tx];
    __syncthreads();
#pragma unroll
    for (int j = 0; j < 4; ++j)
        Bt[(size_t)(n0 + ty + 8 * j) * H_DIM + k0 + tx] = f2bf(tl[tx][ty + 8 * j]);
}

// ---------------- bf16 MFMA GEMM: C[M][N] = A[M][K] * Bt[N][K]^T ----------------
// 128x128 tile, BK=64, 4 waves in 2x2, each wave 64x64 = 4x4 tiles of 16x16x32.
// LDS blocks in fragment-lane order (lane l's 16B at blockbase + l*16).
// Grid swizzle: the 8 bn-blocks of one bm land on ONE XCD (dispatch is
// round-robin mod 8 XCDs), so the A row-tile is fetched once per XCD and
// shared via that XCD's L2 instead of re-fetched 8x from HBM.

#define TM 128
#define TN 128
#define BK 64

__global__ __launch_bounds__(256) void gemm_bf16_kernel(const unsigned short* __restrict__ A,
                                                        const unsigned short* __restrict__ Bt,
                                                        float* __restrict__ C) {
    __shared__ unsigned short As[TM * BK];   // 16 blocks x 512 shorts (16KB)
    __shared__ unsigned short Bs[TN * BK];

    const int tid  = threadIdx.x;
    const int lane = tid & 63;
    const int wid  = tid >> 6;
    const int wm = (wid >> 1) * 64, wn = (wid & 1) * 64;
    const int g  = blockIdx.x;
    const int bn = (g >> 3) & 7;                       // same-XCD blocks cycle bn
    const int bm = ((g >> 6) << 3) | (g & 7);          // bijection onto 0..255
    const int m0 = bm * TM, n0 = bn * TN;

    const int lr = lane & 15;          // row within a 16-row block
    const int lk = (lane >> 4) * 8;    // k offset within a 32-k block

    const unsigned short* ag[4];
    const unsigned short* bg[4];
    unsigned short* asl[4];
    unsigned short* bsl[4];
#pragma unroll
    for (int p = 0; p < 4; ++p) {
        const int ab = wid * 4 + p;
        const int rb = ab >> 1, kb = ab & 1;
        ag[p]  = A  + (size_t)(m0 + rb * 16 + lr) * H_DIM + kb * 32 + lk;
        bg[p]  = Bt + (size_t)(n0 + rb * 16 + lr) * H_DIM + kb * 32 + lk;
        asl[p] = As + ab * 512;
        bsl[p] = Bs + ab * 512;
    }

    floatx4 acc[4][4];
#pragma unroll
    for (int i = 0; i < 4; ++i)
#pragma unroll
        for (int j = 0; j < 4; ++j) acc[i][j] = (floatx4){0.f, 0.f, 0.f, 0.f};

    for (int kt = 0; kt < H_DIM; kt += BK) {
        __syncthreads();
#pragma unroll
        for (int p = 0; p < 4; ++p) {
            __builtin_amdgcn_global_load_lds(
                (const __attribute__((address_space(1))) void*)(ag[p] + kt),
                (__attribute__((address_space(3))) void*)asl[p], 16, 0, 0);
            __builtin_amdgcn_global_load_lds(
                (const __attribute__((address_space(1))) void*)(bg[p] + kt),
                (__attribute__((address_space(3))) void*)bsl[p], 16, 0, 0);
        }
        __syncthreads();
#pragma unroll
        for (int kb = 0; kb < 2; ++kb) {
            bf16x8 af[4], bfv[4];
#pragma unroll
            for (int i = 0; i < 4; ++i) {
                const int rbA = (wm >> 4) + i;
                af[i] = *(const bf16x8*)(As + ((rbA * 2 + kb) << 9) + (lane << 3));
            }
#pragma unroll
            for (int j = 0; j < 4; ++j) {
                const int rbB = (wn >> 4) + j;
                bfv[j] = *(const bf16x8*)(Bs + ((rbB * 2 + kb) << 9) + (lane << 3));
            }
#pragma unroll
            for (int i = 0; i < 4; ++i)
#pragma unroll
                for (int j = 0; j < 4; ++j)
                    acc[i][j] = __builtin_amdgcn_mfma_f32_16x16x32_bf16(af[i], bfv[j], acc[i][j], 0, 0, 0);
        }
    }

    // epilogue: C/D layout col=lane&15, row=(lane>>4)*4+reg  [m89/m91 verified]
    const int cr = (lane >> 4) * 4;
    const int cc = lane & 15;
#pragma unroll
    for (int i = 0; i < 4; ++i)
#pragma unroll
        for (int j = 0; j < 4; ++j) {
            size_t base = (size_t)(m0 + wm + i * 16 + cr) * H_DIM + (n0 + wn + j * 16 + cc);
#pragma unroll
            for (int r = 0; r < 4; ++r)
                C[base + (size_t)r * H_DIM] = acc[i][j][r];
        }
}

// ---------------- fp32 fallback GEMM (only if ws too small) ----------------
__global__ __launch_bounds__(256) void gemm_fp32_fallback(const float* __restrict__ A,
                                                          const float* __restrict__ B,
                                                          float* __restrict__ C) {
    __shared__ float As[64][20];
    __shared__ float Bs[16][68];
    const int tid = threadIdx.x;
    const int bm = blockIdx.x >> 4, bn = blockIdx.x & 15;
    const int m0 = bm * 64, n0 = bn * 64;
    const int tx = (tid & 15) * 4, ty = (tid >> 4) * 4;
    float acc[4][4];
#pragma unroll
    for (int i = 0; i < 4; ++i)
#pragma unroll
        for (int j = 0; j < 4; ++j) acc[i][j] = 0.f;

    for (int kk = 0; kk < H_DIM; kk += 16) {
        float4 av = *(const float4*)(A + (size_t)(m0 + (tid >> 2)) * H_DIM + kk + (tid & 3) * 4);
        float4 bv = *(const float4*)(B + (size_t)(kk + (tid >> 4)) * H_DIM + n0 + (tid & 15) * 4);
        __syncthreads();
        *(float4*)&As[tid >> 2][(tid & 3) * 4] = av;
        *(float4*)&Bs[tid >> 4][(tid & 15) * 4] = bv;
        __syncthreads();
#pragma unroll
        for (int k = 0; k < 16; ++k) {
            float a_[4], b_[4];
#pragma unroll
            for (int i = 0; i < 4; ++i) a_[i] = As[ty + i][k];
#pragma unroll
            for (int j = 0; j < 4; ++j) b_[j] = Bs[k][tx + j];
#pragma unroll
            for (int i = 0; i < 4; ++i)
#pragma unroll
                for (int j = 0; j < 4; ++j) acc[i][j] += a_[i] * b_[j];
        }
    }
#pragma unroll
    for (int i = 0; i < 4; ++i)
#pragma unroll
        for (int j = 0; j < 4; ++j)
            C[(size_t)(m0 + ty + i) * H_DIM + n0 + tx + j] = acc[i][j];
}

// ---------------- sequential scan: ONE WAVE per batch, no barriers ----------------

__device__ __forceinline__ float tanh_fast(float x) {
    float ax = fabsf(x);
    float e  = __expf(-2.0f * ax);
    float t  = (1.0f - e) * __builtin_amdgcn_rcpf(1.0f + e);
    return copysignf(t, x);
}

// DPP wave64 sum: full sum lands in lane 63 (VALU-rate, no LDS).
template <int CTRL, int RMASK>
__device__ __forceinline__ float dpp_add(float x) {
    int v = __builtin_amdgcn_update_dpp(0, __float_as_int(x), CTRL, RMASK, 0xf, true);
    return x + __int_as_float(v);
}
__device__ __forceinline__ float wave_sum64(float x) {
    x = dpp_add<0x111, 0xf>(x);  // row_shr:1
    x = dpp_add<0x112, 0xf>(x);  // row_shr:2
    x = dpp_add<0x114, 0xf>(x);  // row_shr:4
    x = dpp_add<0x118, 0xf>(x);  // row_shr:8  -> lane15 of each row = row sum
    x = dpp_add<0x142, 0xa>(x);  // row_bcast15 -> rows 1,3
    x = dpp_add<0x143, 0xc>(x);  // row_bcast31 -> rows 2,3; lane 63 = total
    return x;
}

__global__ __launch_bounds__(64, 1) void scan_kernel(const float* __restrict__ h0,
                                                     const float* __restrict__ d,
                                                     const float* __restrict__ Lm,
                                                     const float* __restrict__ Rm,
                                                     float* __restrict__ io) {
    const int b    = blockIdx.x;
    const int lane = threadIdx.x;     // 0..63
    const int e0   = lane * 4;        // offset within each 256-elem chunk

    float dd[16], h[16], Lv[16][4], Rv[4][16];
#pragma unroll
    for (int c = 0; c < 4; ++c) {
        float4 t = *(const float4*)(d + c * 256 + e0);
        dd[c*4+0] = t.x; dd[c*4+1] = t.y; dd[c*4+2] = t.z; dd[c*4+3] = t.w;
        float4 hh = *(const float4*)(h0 + (size_t)b * H_DIM + c * 256 + e0);
        h[c*4+0] = hh.x; h[c*4+1] = hh.y; h[c*4+2] = hh.z; h[c*4+3] = hh.w;
    }
#pragma unroll
    for (int c = 0; c < 4; ++c)
#pragma unroll
        for (int q = 0; q < 4; ++q) {
            float4 t = *(const float4*)(Lm + (size_t)(c * 256 + e0 + q) * RANK_);
            Lv[c*4+q][0] = t.x; Lv[c*4+q][1] = t.y; Lv[c*4+q][2] = t.z; Lv[c*4+q][3] = t.w;
        }
#pragma unroll
    for (int j = 0; j < 4; ++j)
#pragma unroll
        for (int c = 0; c < 4; ++c) {
            float4 t = *(const float4*)(Rm + (size_t)j * H_DIM + c * 256 + e0);
            Rv[j][c*4+0] = t.x; Rv[j][c*4+1] = t.y; Rv[j][c*4+2] = t.z; Rv[j][c*4+3] = t.w;
        }

    float* iob = io + (size_t)b * TSTEPS * H_DIM + e0;

    // u prefetch, depth 4 (consumed 4 steps after issue: latency fully hidden)
    float4 u[4][4];
#pragma unroll
    for (int s = 0; s < 4; ++s)
#pragma unroll
        for (int c = 0; c < 4; ++c)
            u[s][c] = *(const float4*)(iob + (size_t)s * H_DIM + c * 256);

    // Output staging: h is copied into o[tt&3] at step tt and STORED at step
    // tt+1 (a real read -> copies can't be elided). o[s] is recycled 4 steps
    // after write, 3 steps after its store issued (~1000 cyc) -> no
    // VMEM-store source-register drain on the critical path.
    float4 o[4][4];

    for (int t = 0; t < TSTEPS; t += 4) {
#pragma unroll
        for (int s = 0; s < 4; ++s) {
            const int tt = t + s;

            float pr[4];
#pragma unroll
            for (int j = 0; j < 4; ++j) {
                float a0 = Rv[j][0] * h[0], a1 = Rv[j][1] * h[1];
                float a2 = Rv[j][2] * h[2], a3 = Rv[j][3] * h[3];
#pragma unroll
                for (int k = 4; k < 16; k += 4) {
                    a0 = fmaf(Rv[j][k+0], h[k+0], a0);
                    a1 = fmaf(Rv[j][k+1], h[k+1], a1);
                    a2 = fmaf(Rv[j][k+2], h[k+2], a2);
                    a3 = fmaf(Rv[j][k+3], h[k+3], a3);
                }
                pr[j] = (a0 + a1) + (a2 + a3);
            }
#pragma unroll
            for (int j = 0; j < 4; ++j) pr[j] = wave_sum64(pr[j]);
            float r[4];
#pragma unroll
            for (int j = 0; j < 4; ++j)
                r[j] = __int_as_float(__builtin_amdgcn_readlane(__float_as_int(pr[j]), 63));

            // store PREVIOUS step's output (pipelined one step late)
            if (tt > 0) {
                const int tp = tt - 1;
#pragma unroll
                for (int c = 0; c < 4; ++c)
                    *(float4*)(iob + (size_t)tp * H_DIM + c * 256) = o[(tp) & 3][c];
            }

#pragma unroll
            for (int c = 0; c < 4; ++c) {
                float uu[4] = {u[s][c].x, u[s][c].y, u[s][c].z, u[s][c].w};
#pragma unroll
                for (int q = 0; q < 4; ++q) {
                    const int k = c * 4 + q;
                    float a = fmaf(dd[k], h[k], uu[q]);
                    a = fmaf(Lv[k][0], r[0], a);
                    a = fmaf(Lv[k][1], r[1], a);
                    a = fmaf(Lv[k][2], r[2], a);
                    a = fmaf(Lv[k][3], r[3], a);
                    h[k] = tanh_fast(a);
                }
                float4 ov; ov.x = h[c*4+0]; ov.y = h[c*4+1]; ov.z = h[c*4+2]; ov.w = h[c*4+3];
                o[s][c] = ov;
            }

            if (tt + 4 < TSTEPS) {
#pragma unroll
                for (int c = 0; c < 4; ++c)
                    u[s][c] = *(const float4*)(iob + (size_t)(tt + 4) * H_DIM + c * 256);
            }
        }
    }
    // final store (tt = 255 lives in o[3])
#pragma unroll
    for (int c = 0; c < 4; ++c)
        *(float4*)(iob + (size_t)(TSTEPS - 1) * H_DIM + c * 256) = o[3][c];
}

// ---------------- launch ----------------

extern "C" void kernel_launch(void* const* d_in, const int* in_sizes, int n_in,
                              void* d_out, int out_size, void* d_ws, size_t ws_size,
                              hipStream_t stream) {
    const float* x  = (const float*)d_in[0];
    const float* h0 = (const float*)d_in[1];
    const float* dd = (const float*)d_in[2];
    const float* L  = (const float*)d_in[3];
    const float* R  = (const float*)d_in[4];
    const float* B  = (const float*)d_in[5];
    float* out = (float*)d_out;

    const size_t need = (size_t)M_DIM * H_DIM * sizeof(unsigned short)
                      + (size_t)H_DIM * H_DIM * sizeof(unsigned short);
    if (ws_size >= need) {
        unsigned short* xb = (unsigned short*)d_ws;
        unsigned short* Bt = xb + (size_t)M_DIM * H_DIM;
        cvt_x_kernel<<<(M_DIM * H_DIM) / (256 * 8), 256, 0, stream>>>(x, xb);
        cvt_bt_kernel<<<dim3(32, 32), 256, 0, stream>>>(B, Bt);
        gemm_bf16_kernel<<<(M_DIM / TM) * (H_DIM / TN), 256, 0, stream>>>(xb, Bt, out);
    } else {
        gemm_fp32_fallback<<<(M_DIM / 64) * (H_DIM / 64), 256, 0, stream>>>(x, B, out);
    }
    scan_kernel<<<BATCH_, 64, 0, stream>>>(h0, dd, L, R, out);
}